// Round 14
// baseline (190.601 us; speedup 1.0000x reference)
//
#include <hip/hip_runtime.h>

// TinyMLP (2 -> 32 -> 32 -> 1, sigmoid) analytic input-gradient, fused, MFMA-based.
// R14: THREE-TILE INTERLEAVE x 3 waves/SIMD (9 contexts) — one rung past R13's
// 2x4 (8 contexts, 95.3us, +17% over R12; chain-parallelism model CONFIRMED).
// Model: throughput = (waves x chains) / chain-latency until VALU-issue ceiling
// (~65-70% practical, m07 calibration). R13 at VALUBusy 60.3% -> ~8-12% headroom.
// Register arithmetic: 72 (base) + 2x36 (extra chains) = 144 <= 170 cap at
// launch_bounds(256,3), grid 768 (3 blocks/CU). Spill tell (R4/R7/R8/R10):
// VGPR_Count drop + FETCH/WRITE balloon -> revert to R13.
// Tail: ntiles % 3 != 0 -> chains B/C use clamped load index (tile 0) + guarded
// store in the single partial group.
//
// Pivot-by-swap (verified-by-run R9/R12/R13): lane n / n+32 jointly hold all 32
// rows of batch col n; v_permlane32_swap_b32 d,s -> d'=[d.lo|s.lo], s'=[d.hi|s.hi].
//   MFMA z1  (x1): -log2e*Z1^T = A_z1 @ Y^T    (y hi/lo bf16 split, b1 in K-slots 6,7)
//   MFMA z2  (x2): -log2e*Z2^T = W2s @ H1^T    (K=32; acc init = -log2e*b2)
//   MFMA dh1 (x2): dH1^T = (W2*W3) @ dZ2^T     (W3 folded into weights at init)
//   MFMA dy  (x2): dY^T  = W1 @ dZ1^T          (g1,g2 = regs 0,1 of lanes 0-31)
// rcp8 sigmoid (verified R12): one v_rcp per 8 denominators, pk product tree.
//
// Layouts (32x32x16 bf16; verified-by-run R5/R9):
//   A-frag: lane holds A[row=lane&31][k=(lane>>5)*8+j]
//   B-frag: lane holds B[k=(lane>>5)*8+j][n=lane&31]
//   C/D:    lane holds D[row=(reg&3)+8*(reg>>2)+4*(lane>>5)][col=lane&31]

#define H 32
#define NLOG2E (-1.4426950408889634f)

typedef __attribute__((ext_vector_type(8))) short bf16x8;
typedef __attribute__((ext_vector_type(16))) float f32x16;
typedef __attribute__((ext_vector_type(2))) float f32x2;
typedef __attribute__((ext_vector_type(2))) __bf16 bfx2;

#define MFMA32 __builtin_amdgcn_mfma_f32_32x32x16_bf16

__device__ __forceinline__ int cvt_pk_bf16(float a, float b) {
    f32x2 f; f[0] = a; f[1] = b;
    bfx2 r = __builtin_convertvector(f, bfx2);   // v_cvt_pk_bf16_f32 (RNE)
    return __builtin_bit_cast(int, r);
}
__device__ __forceinline__ float pklo(int p) {               // low bf16 of packed pair
    unsigned u = (unsigned)p << 16; return __builtin_bit_cast(float, u);
}
__device__ __forceinline__ float pkhi(int p) {               // high bf16 of packed pair
    unsigned u = (unsigned)p & 0xFFFF0000u; return __builtin_bit_cast(float, u);
}

// d.hi <-> s.lo (gfx950): after the asm, d = [d.lo|s.lo], s = [d.hi|s.hi].
__device__ __forceinline__ void plane32_swap(int &d, int &s) {
    asm volatile("v_permlane32_swap_b32 %0, %1" : "+v"(d), "+v"(s));
}

__global__ __launch_bounds__(256, 3) void tinymlp_mfma_kernel(
    const float* __restrict__ x1, const float* __restrict__ x2,
    const float* __restrict__ y1, const float* __restrict__ y2,
    const float* __restrict__ W1, const float* __restrict__ b1,
    const float* __restrict__ W2, const float* __restrict__ b2,
    const float* __restrict__ W3,
    float4* __restrict__ out, int ntiles)
{
    const int tid  = threadIdx.x;
    const int lane = tid & 63;
    const int n    = lane & 31;   // batch column (and weight row for A-frags)
    const int q5   = lane >> 5;   // k-half / h-half selector

    union U4 { int i[4]; bf16x8 v; };
    U4 A_z1, A_z2a, A_z2b, A_dh1a, A_dh1b, A_dya, A_dyb;

    #pragma unroll
    for (int t = 0; t < 4; ++t) {
        const int j0 = 8 * q5 + 2 * t;
        const int j1 = j0 + 1;
        // z2: A[h2=n][k=h1], forward scale folded
        A_z2a.i[t] = cvt_pk_bf16(NLOG2E * W2[j0 * H + n],        NLOG2E * W2[j1 * H + n]);
        A_z2b.i[t] = cvt_pk_bf16(NLOG2E * W2[(16 + j0) * H + n], NLOG2E * W2[(16 + j1) * H + n]);
        // dh1: A[h1=n][k=h2], W3 pre-folded
        A_dh1a.i[t] = cvt_pk_bf16(W2[n * H + j0] * W3[j0],           W2[n * H + j1] * W3[j1]);
        A_dh1b.i[t] = cvt_pk_bf16(W2[n * H + 16 + j0] * W3[16 + j0], W2[n * H + 16 + j1] * W3[16 + j1]);
        // dy: A[c=n][k=h1], rows >= 2 zero
        A_dya.i[t] = (n < 2) ? cvt_pk_bf16(W1[n * H + j0],      W1[n * H + j1])      : 0;
        A_dyb.i[t] = (n < 2) ? cvt_pk_bf16(W1[n * H + 16 + j0], W1[n * H + 16 + j1]) : 0;
    }

    // z1 A-frag: k-slots (q5==0 half): {whi0,whi1, wlo0,wlo1, whi0,whi1, b1hi,b1lo}
    // pairing with B = {y1hi,y2hi, y1hi,y2hi, y1lo,y2lo, 1,1}; q5==1 half all zero.
    A_z1.i[0] = A_z1.i[1] = A_z1.i[2] = A_z1.i[3] = 0;
    if (q5 == 0) {
        const float wa = NLOG2E * W1[n];
        const float wb = NLOG2E * W1[H + n];
        const float bv = NLOG2E * b1[n];
        const int hi  = cvt_pk_bf16(wa, wb);
        const int lo  = cvt_pk_bf16(wa - pklo(hi), wb - pkhi(hi));
        const int bh  = cvt_pk_bf16(bv, 0.f);
        const int bhl = cvt_pk_bf16(bv, bv - pklo(bh));
        A_z1.i[0] = hi; A_z1.i[1] = lo; A_z1.i[2] = hi; A_z1.i[3] = bhl;
    }

    // acc init for z2: -log2e*b2 at rows h2 = (r&3)+8*(r>>2)+4*q5
    f32x16 b2C;
    #pragma unroll
    for (int t = 0; t < 4; ++t) {
        const float4 bt = *(const float4*)&b2[8 * t + 4 * q5];
        b2C[4 * t + 0] = NLOG2E * bt.x; b2C[4 * t + 1] = NLOG2E * bt.y;
        b2C[4 * t + 2] = NLOG2E * bt.z; b2C[4 * t + 3] = NLOG2E * bt.w;
    }

    f32x16 zf16;
    #pragma unroll
    for (int r = 0; r < 16; ++r) zf16[r] = 0.f;

    // ---- per-stage helpers (constant-indexed arrays only) ----
    auto mkY = [&](float a, float b, U4& u) {
        const int hi = cvt_pk_bf16(a, b);
        const int lo = cvt_pk_bf16(a - pklo(hi), b - pkhi(hi));
        u.i[0] = hi; u.i[1] = hi; u.i[2] = lo; u.i[3] = 0x3F803F80;
    };
    // sigmoid of -log2e-scaled z: 16 exp2 + 2 rcp (rcp8 pk tree) -> packed bf16 P[8]
    auto sig8 = [&](const f32x16& z, int* P) {
        #pragma unroll
        for (int h = 0; h < 2; ++h) {
            const int o = 8 * h;
            f32x2 A, Bv, Cv, Dv;
            A[0]  = __builtin_amdgcn_exp2f(z[o + 0]);
            A[1]  = __builtin_amdgcn_exp2f(z[o + 1]);
            Bv[0] = __builtin_amdgcn_exp2f(z[o + 2]);
            Bv[1] = __builtin_amdgcn_exp2f(z[o + 3]);
            Cv[0] = __builtin_amdgcn_exp2f(z[o + 4]);
            Cv[1] = __builtin_amdgcn_exp2f(z[o + 5]);
            Dv[0] = __builtin_amdgcn_exp2f(z[o + 6]);
            Dv[1] = __builtin_amdgcn_exp2f(z[o + 7]);
            A += 1.0f; Bv += 1.0f; Cv += 1.0f; Dv += 1.0f;        // v_pk_add_f32
            const f32x2 M1 = A * Bv, M2 = Cv * Dv, M = M1 * M2;   // v_pk_mul_f32
            const float r = __builtin_amdgcn_rcpf(M[0] * M[1]);   // prod8 <= 257^8
            f32x2 R; R[0] = r * M[1]; R[1] = r * M[0];
            const f32x2 N1 = R * M2, N2 = R * M1;
            const f32x2 S0 = Bv * N1, S1 = A * N1, S2 = Dv * N2, S3 = Cv * N2;
            P[4 * h + 0] = cvt_pk_bf16(S0[0], S0[1]);
            P[4 * h + 1] = cvt_pk_bf16(S1[0], S1[1]);
            P[4 * h + 2] = cvt_pk_bf16(S2[0], S2[1]);
            P[4 * h + 3] = cvt_pk_bf16(S3[0], S3[1]);
        }
    };
    // pivot packed C-ints -> two B-frags, preserving P (copies then swap)
    auto pivP = [&](const int* P, U4& F1, U4& F2) {
        int a0 = P[0], a2 = P[2]; plane32_swap(a0, a2);
        int a1 = P[1], a3 = P[3]; plane32_swap(a1, a3);
        F1.i[0] = a0; F1.i[1] = a1; F1.i[2] = a2; F1.i[3] = a3;
        int b0 = P[4], b2i = P[6]; plane32_swap(b0, b2i);
        int b1i = P[5], b3 = P[7]; plane32_swap(b1i, b3);
        F2.i[0] = b0; F2.i[1] = b1i; F2.i[2] = b2i; F2.i[3] = b3;
    };
    // dz2 = s2(1-s2) straight into B-frag unions, swap in place
    auto dz2f = [&](const f32x16& zz, U4& D1, U4& D2) {
        #pragma unroll
        for (int h = 0; h < 2; ++h) {
            const int o = 8 * h;
            f32x2 A, Bv, Cv, Dv;
            A[0]  = __builtin_amdgcn_exp2f(zz[o + 0]);
            A[1]  = __builtin_amdgcn_exp2f(zz[o + 1]);
            Bv[0] = __builtin_amdgcn_exp2f(zz[o + 2]);
            Bv[1] = __builtin_amdgcn_exp2f(zz[o + 3]);
            Cv[0] = __builtin_amdgcn_exp2f(zz[o + 4]);
            Cv[1] = __builtin_amdgcn_exp2f(zz[o + 5]);
            Dv[0] = __builtin_amdgcn_exp2f(zz[o + 6]);
            Dv[1] = __builtin_amdgcn_exp2f(zz[o + 7]);
            A += 1.0f; Bv += 1.0f; Cv += 1.0f; Dv += 1.0f;
            const f32x2 M1 = A * Bv, M2 = Cv * Dv, M = M1 * M2;
            const float r = __builtin_amdgcn_rcpf(M[0] * M[1]);
            f32x2 R; R[0] = r * M[1]; R[1] = r * M[0];
            const f32x2 N1 = R * M2, N2 = R * M1;
            f32x2 S0 = Bv * N1, S1 = A * N1, S2 = Dv * N2, S3 = Cv * N2;
            S0 = __builtin_elementwise_fma(-S0, S0, S0);
            S1 = __builtin_elementwise_fma(-S1, S1, S1);
            S2 = __builtin_elementwise_fma(-S2, S2, S2);
            S3 = __builtin_elementwise_fma(-S3, S3, S3);
            U4& Df = h ? D2 : D1;
            Df.i[0] = cvt_pk_bf16(S0[0], S0[1]);
            Df.i[1] = cvt_pk_bf16(S1[0], S1[1]);
            Df.i[2] = cvt_pk_bf16(S2[0], S2[1]);
            Df.i[3] = cvt_pk_bf16(S3[0], S3[1]);
        }
        plane32_swap(D1.i[0], D1.i[2]);
        plane32_swap(D1.i[1], D1.i[3]);
        plane32_swap(D2.i[0], D2.i[2]);
        plane32_swap(D2.i[1], D2.i[3]);
    };
    // dz1 = dH1 * h1d straight into B-frag unions, swap in place
    auto dz1f = [&](const f32x16& dh, const int* P, U4& E1, U4& E2) {
        #pragma unroll
        for (int t = 0; t < 4; ++t) {
            U4& Ef = (t & 2) ? E2 : E1;
            const int sl = 2 * (t & 1);
            f32x2 sv, gg;
            sv[0] = pklo(P[2 * t]); sv[1] = pkhi(P[2 * t]);
            sv = __builtin_elementwise_fma(-sv, sv, sv);
            gg[0] = dh[4 * t]; gg[1] = dh[4 * t + 1]; gg *= sv;
            Ef.i[sl] = cvt_pk_bf16(gg[0], gg[1]);
            sv[0] = pklo(P[2 * t + 1]); sv[1] = pkhi(P[2 * t + 1]);
            sv = __builtin_elementwise_fma(-sv, sv, sv);
            gg[0] = dh[4 * t + 2]; gg[1] = dh[4 * t + 3]; gg *= sv;
            Ef.i[sl + 1] = cvt_pk_bf16(gg[0], gg[1]);
        }
        plane32_swap(E1.i[0], E1.i[2]);
        plane32_swap(E1.i[1], E1.i[3]);
        plane32_swap(E2.i[0], E2.i[2]);
        plane32_swap(E2.i[1], E2.i[3]);
    };

    const int gwave   = (blockIdx.x * blockDim.x + tid) >> 6;
    const int nwaves  = (gridDim.x * blockDim.x) >> 6;
    const int ngroups = (ntiles + 2) / 3;                 // groups of 3 tiles
    const unsigned Btot = (unsigned)ntiles * 32u;
    unsigned e0 = (unsigned)gwave * 96;                   // group base element
    const unsigned step = (unsigned)nwaves * 96;

    for (int g = gwave; g < ngroups; g += nwaves) {
        // chain element indices; B/C clamp to tile 0 in the single partial group
        const unsigned iA = e0 + (unsigned)n;
        const bool okB = (e0 + 32) < Btot;
        const bool okC = (e0 + 64) < Btot;
        const unsigned iB = okB ? iA + 32 : (unsigned)n;
        const unsigned iC = okC ? iA + 64 : (unsigned)n;

        float yA1 = 0.f, yA2 = 0.f, xA1 = 0.f, xA2 = 0.f;
        float yB1 = 0.f, yB2 = 0.f, xB1 = 0.f, xB2 = 0.f;
        float yC1 = 0.f, yC2 = 0.f, xC1 = 0.f, xC2 = 0.f;
        if (lane < 32) {
            yA1 = y1[iA]; yA2 = y2[iA]; xA1 = x1[iA]; xA2 = x2[iA];
            yB1 = y1[iB]; yB2 = y2[iB]; xB1 = x1[iB]; xB2 = x2[iB];
            yC1 = y1[iC]; yC2 = y2[iC]; xC1 = x1[iC]; xC2 = x2[iC];
        }

        // ---- stage-interleaved A/B/C: zero barriers -> three independent chains ----
        U4 uYA, uYB, uYC;
        mkY(yA1, yA2, uYA);
        mkY(yB1, yB2, uYB);
        mkY(yC1, yC2, uYC);
        const f32x16 accA = MFMA32(A_z1.v, uYA.v, zf16, 0, 0, 0);
        const f32x16 accB = MFMA32(A_z1.v, uYB.v, zf16, 0, 0, 0);
        const f32x16 accC = MFMA32(A_z1.v, uYC.v, zf16, 0, 0, 0);

        int PA[8], PB[8], PC[8];
        sig8(accA, PA);
        sig8(accB, PB);
        sig8(accC, PC);

        U4 B1A, B2A, B1B, B2B, B1C, B2C_;
        pivP(PA, B1A, B2A);
        pivP(PB, B1B, B2B);
        pivP(PC, B1C, B2C_);

        f32x16 zzA = MFMA32(A_z2a.v, B1A.v, b2C, 0, 0, 0);
        f32x16 zzB = MFMA32(A_z2a.v, B1B.v, b2C, 0, 0, 0);
        f32x16 zzC = MFMA32(A_z2a.v, B1C.v, b2C, 0, 0, 0);
        zzA = MFMA32(A_z2b.v, B2A.v, zzA, 0, 0, 0);
        zzB = MFMA32(A_z2b.v, B2B.v, zzB, 0, 0, 0);
        zzC = MFMA32(A_z2b.v, B2C_.v, zzC, 0, 0, 0);

        U4 D1A, D2A, D1B, D2B, D1C, D2C;
        dz2f(zzA, D1A, D2A);
        dz2f(zzB, D1B, D2B);
        dz2f(zzC, D1C, D2C);

        f32x16 dhA = MFMA32(A_dh1a.v, D1A.v, zf16, 0, 0, 0);
        f32x16 dhB = MFMA32(A_dh1a.v, D1B.v, zf16, 0, 0, 0);
        f32x16 dhC = MFMA32(A_dh1a.v, D1C.v, zf16, 0, 0, 0);
        dhA = MFMA32(A_dh1b.v, D2A.v, dhA, 0, 0, 0);
        dhB = MFMA32(A_dh1b.v, D2B.v, dhB, 0, 0, 0);
        dhC = MFMA32(A_dh1b.v, D2C.v, dhC, 0, 0, 0);

        U4 E1A, E2A, E1B, E2B, E1C, E2C;
        dz1f(dhA, PA, E1A, E2A);
        dz1f(dhB, PB, E1B, E2B);
        dz1f(dhC, PC, E1C, E2C);

        f32x16 ayA = MFMA32(A_dya.v, E1A.v, zf16, 0, 0, 0);
        f32x16 ayB = MFMA32(A_dya.v, E1B.v, zf16, 0, 0, 0);
        f32x16 ayC = MFMA32(A_dya.v, E1C.v, zf16, 0, 0, 0);
        ayA = MFMA32(A_dyb.v, E2A.v, ayA, 0, 0, 0);
        ayB = MFMA32(A_dyb.v, E2B.v, ayB, 0, 0, 0);
        ayC = MFMA32(A_dyb.v, E2C.v, ayC, 0, 0, 0);

        if (lane < 32) {
            float4 o;
            o.x = xA1 + ayA[0]; o.y = xA2 + ayA[1]; o.z = yA1; o.w = yA2;
            out[iA] = o;
            if (okB) {
                o.x = xB1 + ayB[0]; o.y = xB2 + ayB[1]; o.z = yB1; o.w = yB2;
                out[iB] = o;
            }
            if (okC) {
                o.x = xC1 + ayC[0]; o.y = xC2 + ayC[1]; o.z = yC1; o.w = yC2;
                out[iC] = o;
            }
        }

        e0 += step;
    }
}

extern "C" void kernel_launch(void* const* d_in, const int* in_sizes, int n_in,
                              void* d_out, int out_size, void* d_ws, size_t ws_size,
                              hipStream_t stream) {
    const float* x1 = (const float*)d_in[0];
    const float* x2 = (const float*)d_in[1];
    const float* y1 = (const float*)d_in[2];
    const float* y2 = (const float*)d_in[3];
    const float* W1 = (const float*)d_in[4];
    const float* b1 = (const float*)d_in[5];
    const float* W2 = (const float*)d_in[6];
    const float* b2 = (const float*)d_in[7];
    const float* W3 = (const float*)d_in[8];
    // d_in[9] = b3: drops out of the input-gradient — unused.

    const int n = in_sizes[0];
    const int ntiles = n / 32;       // B = 4194304 -> 131072 tiles of 32
    const int block = 256;           // 4 waves
    const int grid = 768;            // 3 blocks/CU -> 3 waves/SIMD, VGPR cap 170
    tinymlp_mfma_kernel<<<grid, block, 0, stream>>>(
        x1, x2, y1, y2, W1, b1, W2, b2, W3, (float4*)d_out, ntiles);
}